// Round 4
// baseline (487.547 us; speedup 1.0000x reference)
//
#include <hip/hip_runtime.h>
#include <hip/hip_bf16.h>

#define T_LEN 2048
#define D_DIM 1024
#define H_NUM 16
#define DK 64

typedef unsigned short u16;
typedef __bf16 bf16x8 __attribute__((ext_vector_type(8)));
typedef float f32x4 __attribute__((ext_vector_type(4)));
typedef u16 u16x8 __attribute__((ext_vector_type(8)));
typedef u16 u16x4 __attribute__((ext_vector_type(4)));

#define AS1 __attribute__((address_space(1)))
#define AS3 __attribute__((address_space(3)))

__device__ __forceinline__ u16 f2bf(float f) {
    unsigned u = __builtin_bit_cast(unsigned, f);
    unsigned rounding = 0x7FFFu + ((u >> 16) & 1u);
    return (u16)((u + rounding) >> 16);
}

// ---------------- f32 -> bf16 conversion (8 elems / thread) ----------------
__global__ __launch_bounds__(256) void cvt_bf16(const float* __restrict__ in,
                                                u16* __restrict__ out, int n8) {
    int i = blockIdx.x * blockDim.x + threadIdx.x;
    if (i >= n8) return;
    const float4* p = (const float4*)in + (size_t)i * 2;
    float4 a = p[0], b = p[1];
    u16x8 r;
    r[0] = f2bf(a.x); r[1] = f2bf(a.y); r[2] = f2bf(a.z); r[3] = f2bf(a.w);
    r[4] = f2bf(b.x); r[5] = f2bf(b.y); r[6] = f2bf(b.z); r[7] = f2bf(b.w);
    *((u16x8*)out + i) = r;
}

// 4 equal-size f32->bf16 segments (the four weight matrices), dst contiguous.
__global__ __launch_bounds__(256) void cvt4_bf16(const float* __restrict__ a,
                                                 const float* __restrict__ b,
                                                 const float* __restrict__ c,
                                                 const float* __restrict__ d,
                                                 u16* __restrict__ out, int n8per) {
    int s = blockIdx.y;
    const float* src = s == 0 ? a : (s == 1 ? b : (s == 2 ? c : d));
    int i = blockIdx.x * blockDim.x + threadIdx.x;
    if (i >= n8per) return;
    const float4* p = (const float4*)src + (size_t)i * 2;
    float4 x = p[0], y = p[1];
    u16x8 r;
    r[0] = f2bf(x.x); r[1] = f2bf(x.y); r[2] = f2bf(x.z); r[3] = f2bf(x.w);
    r[4] = f2bf(y.x); r[5] = f2bf(y.y); r[6] = f2bf(y.z); r[7] = f2bf(y.w);
    *((u16x8*)(out + (size_t)s * n8per * 8) + i) = r;
}

// ---------------- GEMM: C[M,N] = A[M,K] * W[N,K]^T + bias ----------------
// 1-D grid with XCD-aware decode: each XCD owns a disjoint x-range (A-panels
// L2-resident, fetched once chip-wide); y sweeps fastest within an x-group.
template <int MODE>
__global__ __launch_bounds__(256) void gemm_bt(const u16* __restrict__ A,
                                               const u16* __restrict__ W,
                                               const float* __restrict__ b0,
                                               const float* __restrict__ b1,
                                               const float* __restrict__ b2,
                                               void* __restrict__ Cout,
                                               int M, int N, int K,
                                               int nxt, int nyt) {
    __shared__ u16 lA[128 * 32];
    __shared__ u16 lB[128 * 32];
    const int tid = threadIdx.x;
    const int w = tid >> 6, lane = tid & 63;

    const int bid = blockIdx.x;
    const int idx = bid >> 3;
    const int y = idx % nyt;
    const int x = (bid & 7) * (nxt >> 3) + idx / nyt;
    const int tm = x * 128;
    const int tn = y * 128;

    const int wm = (w >> 1) * 64, wn = (w & 1) * 64;
    const int kgrp = (lane >> 4) * 8;

    f32x4 acc[4][4] = {};

    for (int k0 = 0; k0 < K; k0 += 32) {
        __syncthreads();
#pragma unroll
        for (int r = 0; r < 2; ++r) {
            int c = r * 256 + tid;
            int row = c >> 2, col = (c & 3) * 8;
            const u16* ga = A + (size_t)(tm + row) * K + k0 + col;
            const u16* gb = W + (size_t)(tn + row) * K + k0 + col;
            __builtin_amdgcn_global_load_lds((AS1 const void*)ga,
                (AS3 void*)(lA + (size_t)(r * 256 + w * 64) * 8), 16, 0, 0);
            __builtin_amdgcn_global_load_lds((AS1 const void*)gb,
                (AS3 void*)(lB + (size_t)(r * 256 + w * 64) * 8), 16, 0, 0);
        }
        __syncthreads();

        bf16x8 af[4], bfr[4];
#pragma unroll
        for (int i = 0; i < 4; ++i) {
            af[i]  = *(const bf16x8*)(lA + (wm + i * 16 + (lane & 15)) * 32 + kgrp);
            bfr[i] = *(const bf16x8*)(lB + (wn + i * 16 + (lane & 15)) * 32 + kgrp);
        }
#pragma unroll
        for (int mi = 0; mi < 4; ++mi)
#pragma unroll
            for (int ni = 0; ni < 4; ++ni)
                acc[mi][ni] = __builtin_amdgcn_mfma_f32_16x16x32_bf16(
                    af[mi], bfr[ni], acc[mi][ni], 0, 0, 0);
    }

    const int mtx = tn >> 10;                       // which weight panel
    const float* bp = mtx == 0 ? b0 : (mtx == 1 ? b1 : b2);
    const int crow0 = (lane >> 4) * 4;
    const int ccol = lane & 15;
#pragma unroll
    for (int mi = 0; mi < 4; ++mi) {
#pragma unroll
        for (int ni = 0; ni < 4; ++ni) {
            int n = tn + wn + ni * 16 + ccol;
            float bv = bp[n & 1023];
#pragma unroll
            for (int r = 0; r < 4; ++r) {
                int m = tm + wm + mi * 16 + crow0 + r;
                float val = acc[mi][ni][r] + bv;
                if (MODE == 0) {
                    ((float*)Cout)[(size_t)m * N + n] = val;
                } else {
                    int b = m >> 11, t = m & (T_LEN - 1);
                    int nn = n & 1023;
                    int h = nn >> 6, d = nn & 63;
                    ((u16*)Cout)[(size_t)mtx * 8388608 +
                                 ((size_t)(b * H_NUM + h) * T_LEN + t) * DK + d] = f2bf(val);
                }
            }
        }
    }
}

// ---------------- Flash attention, causal, load-balanced + pipelined --------
// grid 1024 (XCD-decoded), block 256 (4 waves). Block handles q-block pair
// {bx, 31-bx} of 64 rows each: 33 KV-tiles for EVERY block. Wave w owns 16
// q-rows. Double-buffered lK/lV, one barrier per KV tile, defer-max softmax.
__global__ __launch_bounds__(256, 4) void attn_fwd(const u16* __restrict__ q,
                                                   const u16* __restrict__ k,
                                                   const u16* __restrict__ v,
                                                   u16* __restrict__ o) {
    __shared__ u16 lK[2][64 * 64];   // [key][d], 16B-window ^= key&7
    __shared__ u16 lV[2][64 * 64];   // [d][key], 16B-window ^= (d>>1)&7
    __shared__ u16 lP[4][16 * 64];   // per-wave P roundtrip (swizzled)

    const int tid = threadIdx.x, w = tid >> 6, lane = tid & 63;
    const int bid = blockIdx.x;
    const int idx = bid >> 3;
    const int bh = (bid & 7) * 8 + (idx >> 4);   // all 16 bx of a head on 1 XCD
    const int bx = idx & 15;

    const u16* qb = q + (size_t)bh * T_LEN * DK;
    const u16* kb = k + (size_t)bh * T_LEN * DK;
    const u16* vb = v + (size_t)bh * T_LEN * DK;

    const int g = lane >> 4;       // k-group within MFMA
    const int ccol = lane & 15;
    const int kg = tid >> 4;       // V-stage: key group (4 keys)
    const int dc = tid & 15;       // V-stage: d group (4 d)
    const int b_ = bh >> 4, h_ = bh & 15;

    for (int seg = 0; seg < 2; ++seg) {
        const int qblk = seg ? (31 - bx) : bx;
        const int q0 = qblk * 64;
        const int ntiles = qblk + 1;
        const int rowbase = q0 + w * 16;

        // Q fragments (A-frag: row = lane&15)
        bf16x8 qa[2];
#pragma unroll
        for (int kk = 0; kk < 2; ++kk)
            qa[kk] = *(const bf16x8*)(qb + (size_t)(rowbase + ccol) * DK + kk * 32 + g * 8);

        f32x4 oacc[4] = {};
        float mrow[4], lrow[4];
#pragma unroll
        for (int r = 0; r < 4; ++r) { mrow[r] = -1e30f; lrow[r] = 0.f; }

        // ---- prologue: issue tile 0 (buffer 0) ----
        u16x4 vr[4];
#pragma unroll
        for (int r2 = 0; r2 < 2; ++r2) {
            int c = r2 * 256 + tid, row = c >> 3, ch = c & 7;
            __builtin_amdgcn_global_load_lds(
                (AS1 const void*)(kb + (size_t)row * DK + (ch ^ (row & 7)) * 8),
                (AS3 void*)(&lK[0][(r2 * 256 + w * 64) * 8]), 16, 0, 0);
        }
#pragma unroll
        for (int i = 0; i < 4; ++i)
            vr[i] = *(const u16x4*)(vb + (size_t)(kg * 4 + i) * DK + dc * 4);

        for (int kt = 0; kt < ntiles; ++kt) {
            const int bf = kt & 1;
            const int kv0 = kt << 6;
            asm volatile("s_waitcnt vmcnt(0)" ::: "memory");
            // scatter V(kt) -> lV[bf] (transposed, swizzled, b64 writes)
#pragma unroll
            for (int j = 0; j < 4; ++j) {
                int d = dc * 4 + j;
                u16x4 t4;
                t4[0] = vr[0][j]; t4[1] = vr[1][j]; t4[2] = vr[2][j]; t4[3] = vr[3][j];
                *(u16x4*)(&lV[bf][d * 64 + (((kg >> 1) ^ ((d >> 1) & 7)) * 8 + (kg & 1) * 4)]) = t4;
            }
            __syncthreads();

            // issue tile kt+1 into buffers bf^1 (hidden under compute)
            if (kt + 1 < ntiles) {
                const int kvn = (kt + 1) << 6;
#pragma unroll
                for (int r2 = 0; r2 < 2; ++r2) {
                    int c = r2 * 256 + tid, row = c >> 3, ch = c & 7;
                    __builtin_amdgcn_global_load_lds(
                        (AS1 const void*)(kb + (size_t)(kvn + row) * DK + (ch ^ (row & 7)) * 8),
                        (AS3 void*)(&lK[bf ^ 1][(r2 * 256 + w * 64) * 8]), 16, 0, 0);
                }
#pragma unroll
                for (int i = 0; i < 4; ++i)
                    vr[i] = *(const u16x4*)(vb + (size_t)(kvn + kg * 4 + i) * DK + dc * 4);
            }

            // hoist V fragments
            bf16x8 vf[4][2];
            const int vsw = (ccol >> 1) & 7;
#pragma unroll
            for (int nt2 = 0; nt2 < 4; ++nt2)
#pragma unroll
                for (int kk2 = 0; kk2 < 2; ++kk2)
                    vf[nt2][kk2] = *(const bf16x8*)(&lV[bf][(nt2 * 16 + ccol) * 64 +
                                                    (((kk2 * 4 + g) ^ vsw) * 8)]);

            // S = Q K^T * scale   (16 q-rows x 64 keys)
            f32x4 sacc[4] = {};
#pragma unroll
            for (int nt = 0; nt < 4; ++nt)
#pragma unroll
                for (int kk = 0; kk < 2; ++kk) {
                    bf16x8 kf = *(const bf16x8*)(&lK[bf][(nt * 16 + ccol) * 64 +
                                                 (((kk * 4 + g) ^ (ccol & 7)) * 8)]);
                    sacc[nt] = __builtin_amdgcn_mfma_f32_16x16x32_bf16(
                        qa[kk], kf, sacc[nt], 0, 0, 0);
                }

            const bool full = (kv0 + 63) <= rowbase;  // wave-uniform
            float p[4][4], scal[4];
            bool anyresc = false;
#pragma unroll
            for (int r = 0; r < 4; ++r) {
                int grow = rowbase + g * 4 + r;
                float s[4], mx = -1e30f;
#pragma unroll
                for (int nt = 0; nt < 4; ++nt) {
                    float sv = sacc[nt][r] * 0.125f;
                    if (!full && (kv0 + nt * 16 + ccol > grow)) sv = -1e30f;
                    s[nt] = sv;
                    mx = fmaxf(mx, sv);
                }
#pragma unroll
                for (int off = 8; off; off >>= 1) mx = fmaxf(mx, __shfl_xor(mx, off));
                const bool skiprow = (mx <= mrow[r] + 8.f);   // defer-max (T13)
                float mnew = skiprow ? mrow[r] : mx;
                float rs = 0.f;
#pragma unroll
                for (int nt = 0; nt < 4; ++nt) {
                    p[nt][r] = __expf(s[nt] - mnew);
                    rs += p[nt][r];
                }
#pragma unroll
                for (int off = 8; off; off >>= 1) rs += __shfl_xor(rs, off);
                scal[r] = skiprow ? 1.f : __expf(mrow[r] - mnew);
                anyresc |= !skiprow;
                lrow[r] = lrow[r] * scal[r] + rs;
                mrow[r] = mnew;
            }
            if (__any(anyresc)) {
#pragma unroll
                for (int nt2 = 0; nt2 < 4; ++nt2)
#pragma unroll
                    for (int r = 0; r < 4; ++r) oacc[nt2][r] *= scal[r];
            }

            // P -> per-wave LDS (swizzled), read back as A-frags
#pragma unroll
            for (int nt = 0; nt < 4; ++nt)
#pragma unroll
                for (int r = 0; r < 4; ++r) {
                    int qrow = g * 4 + r;
                    int swzq = ((qrow ^ (qrow >> 3)) & 7) * 8;
                    lP[w][qrow * 64 + ((nt * 16 + ccol) ^ swzq)] = f2bf(p[nt][r]);
                }
            asm volatile("s_waitcnt lgkmcnt(0)" ::: "memory");
            bf16x8 pa[2];
            {
                int swzr = (ccol ^ (ccol >> 3)) & 7;
#pragma unroll
                for (int kk2 = 0; kk2 < 2; ++kk2)
                    pa[kk2] = *(const bf16x8*)(&lP[w][ccol * 64 +
                                               ((kk2 * 4 + g) ^ swzr) * 8]);
            }
#pragma unroll
            for (int nt2 = 0; nt2 < 4; ++nt2)
#pragma unroll
                for (int kk2 = 0; kk2 < 2; ++kk2)
                    oacc[nt2] = __builtin_amdgcn_mfma_f32_16x16x32_bf16(
                        pa[kk2], vf[nt2][kk2], oacc[nt2], 0, 0, 0);
        }
        __syncthreads();  // protect LDS buffers before next seg's prologue

        // epilogue: normalize, store bf16 at [b*T+t][h*64+d]
#pragma unroll
        for (int r = 0; r < 4; ++r) {
            float inv = 1.0f / lrow[r];
            int trow = rowbase + g * 4 + r;
#pragma unroll
            for (int nt2 = 0; nt2 < 4; ++nt2) {
                float val = oacc[nt2][r] * inv;
                o[(size_t)(b_ * T_LEN + trow) * D_DIM + h_ * DK + nt2 * 16 + ccol] = f2bf(val);
            }
        }
    }
}

// ---------------- launch ----------------
extern "C" void kernel_launch(void* const* d_in, const int* in_sizes, int n_in,
                              void* d_out, int out_size, void* d_ws, size_t ws_size,
                              hipStream_t stream) {
    const float* x  = (const float*)d_in[0];
    const float* Wq = (const float*)d_in[2];
    const float* Wk = (const float*)d_in[3];
    const float* Wv = (const float*)d_in[4];
    const float* Wo = (const float*)d_in[5];
    const float* bq = (const float*)d_in[6];
    const float* bk = (const float*)d_in[7];
    const float* bv = (const float*)d_in[8];
    const float* bo = (const float*)d_in[9];

    char* ws = (char*)d_ws;
    u16* xb   = (u16*)(ws);                    // 16 MB, reused as attn output
    u16* wqb  = (u16*)(ws + 16777216);         // wq|wk|wv|wo contiguous 2MB each
    u16* wob  = (u16*)(ws + 23068672);
    u16* qws  = (u16*)(ws + 25165824);         // q|k|v contiguous 16MB each
    u16* kws  = (u16*)(ws + 41943040);
    u16* vws  = (u16*)(ws + 58720256);
    u16* attnb = xb;

    cvt_bf16<<<4096, 256, 0, stream>>>(x, xb, 1048576);
    cvt4_bf16<<<dim3(512, 4), 256, 0, stream>>>(Wq, Wk, Wv, Wo, wqb, 131072);

    // fused QKV projection: N = 3072 (wq|wk|wv panels)
    gemm_bt<1><<<1536, 256, 0, stream>>>(xb, wqb, bq, bk, bv, qws, 8192, 3072, 1024, 64, 24);

    attn_fwd<<<1024, 256, 0, stream>>>(qws, kws, vws, attnb);

    gemm_bt<0><<<512, 256, 0, stream>>>(attnb, wob, bo, bo, bo, d_out, 8192, 1024, 1024, 64, 8);
}

// Round 5
// 330.487 us; speedup vs baseline: 1.4752x; 1.4752x over previous
//
#include <hip/hip_runtime.h>
#include <hip/hip_bf16.h>

#define T_LEN 2048
#define D_DIM 1024
#define H_NUM 16
#define DK 64

typedef unsigned short u16;
typedef __bf16 bf16x8 __attribute__((ext_vector_type(8)));
typedef float f32x4 __attribute__((ext_vector_type(4)));
typedef u16 u16x8 __attribute__((ext_vector_type(8)));
typedef u16 u16x4 __attribute__((ext_vector_type(4)));

#define AS1 __attribute__((address_space(1)))
#define AS3 __attribute__((address_space(3)))

// Q pre-scale: 1/sqrt(64) * log2(e)  (softmax done in exp2 domain)
#define QSCALE 0.18033688011112042f

__device__ __forceinline__ u16 f2bf(float f) {
    unsigned u = __builtin_bit_cast(unsigned, f);
    unsigned rounding = 0x7FFFu + ((u >> 16) & 1u);
    return (u16)((u + rounding) >> 16);
}

// ---------------- f32 -> bf16 conversion (8 elems / thread) ----------------
__global__ __launch_bounds__(256) void cvt_bf16(const float* __restrict__ in,
                                                u16* __restrict__ out, int n8) {
    int i = blockIdx.x * blockDim.x + threadIdx.x;
    if (i >= n8) return;
    const float4* p = (const float4*)in + (size_t)i * 2;
    float4 a = p[0], b = p[1];
    u16x8 r;
    r[0] = f2bf(a.x); r[1] = f2bf(a.y); r[2] = f2bf(a.z); r[3] = f2bf(a.w);
    r[4] = f2bf(b.x); r[5] = f2bf(b.y); r[6] = f2bf(b.z); r[7] = f2bf(b.w);
    *((u16x8*)out + i) = r;
}

__global__ __launch_bounds__(256) void cvt4_bf16(const float* __restrict__ a,
                                                 const float* __restrict__ b,
                                                 const float* __restrict__ c,
                                                 const float* __restrict__ d,
                                                 u16* __restrict__ out, int n8per) {
    int s = blockIdx.y;
    const float* src = s == 0 ? a : (s == 1 ? b : (s == 2 ? c : d));
    int i = blockIdx.x * blockDim.x + threadIdx.x;
    if (i >= n8per) return;
    const float4* p = (const float4*)src + (size_t)i * 2;
    float4 x = p[0], y = p[1];
    u16x8 r;
    r[0] = f2bf(x.x); r[1] = f2bf(x.y); r[2] = f2bf(x.z); r[3] = f2bf(x.w);
    r[4] = f2bf(y.x); r[5] = f2bf(y.y); r[6] = f2bf(y.z); r[7] = f2bf(y.w);
    *((u16x8*)(out + (size_t)s * n8per * 8) + i) = r;
}

// ---------------- GEMM: C[M,N] = A[M,K] * W[N,K]^T + bias ----------------
// 2-phase double-buffered K-loop (issue next tile's global_load_lds before
// compute; single vmcnt(0)+barrier per K-step). XCD-aware 1-D grid decode.
// MODE 1 additionally pre-scales the q panel (mtx==0) by QSCALE.
template <int MODE>
__global__ __launch_bounds__(256) void gemm_bt(const u16* __restrict__ A,
                                               const u16* __restrict__ W,
                                               const float* __restrict__ b0,
                                               const float* __restrict__ b1,
                                               const float* __restrict__ b2,
                                               void* __restrict__ Cout,
                                               int M, int N, int K,
                                               int nxt, int nyt) {
    __shared__ u16 lA[2][128 * 32];
    __shared__ u16 lB[2][128 * 32];
    const int tid = threadIdx.x;
    const int w = tid >> 6, lane = tid & 63;

    const int bid = blockIdx.x;
    const int idx = bid >> 3;
    const int y = idx % nyt;
    const int x = (bid & 7) * (nxt >> 3) + idx / nyt;
    const int tm = x * 128;
    const int tn = y * 128;

    const int wm = (w >> 1) * 64, wn = (w & 1) * 64;
    const int kgrp = (lane >> 4) * 8;

    f32x4 acc[4][4] = {};

    auto stage = [&](int buf, int k0) {
#pragma unroll
        for (int r = 0; r < 2; ++r) {
            int c = r * 256 + tid;
            int row = c >> 2, col = (c & 3) * 8;
            __builtin_amdgcn_global_load_lds(
                (AS1 const void*)(A + (size_t)(tm + row) * K + k0 + col),
                (AS3 void*)(&lA[buf][(r * 256 + w * 64) * 8]), 16, 0, 0);
            __builtin_amdgcn_global_load_lds(
                (AS1 const void*)(W + (size_t)(tn + row) * K + k0 + col),
                (AS3 void*)(&lB[buf][(r * 256 + w * 64) * 8]), 16, 0, 0);
        }
    };

    stage(0, 0);
    asm volatile("s_waitcnt vmcnt(0)" ::: "memory");
    __syncthreads();

    const int niter = K >> 5;
    for (int it = 0; it < niter; ++it) {
        const int cur = it & 1;
        if (it + 1 < niter) stage(cur ^ 1, (it + 1) << 5);

        bf16x8 af[4], bfr[4];
#pragma unroll
        for (int i = 0; i < 4; ++i) {
            af[i]  = *(const bf16x8*)(&lA[cur][(wm + i * 16 + (lane & 15)) * 32 + kgrp]);
            bfr[i] = *(const bf16x8*)(&lB[cur][(wn + i * 16 + (lane & 15)) * 32 + kgrp]);
        }
#pragma unroll
        for (int mi = 0; mi < 4; ++mi)
#pragma unroll
            for (int ni = 0; ni < 4; ++ni)
                acc[mi][ni] = __builtin_amdgcn_mfma_f32_16x16x32_bf16(
                    af[mi], bfr[ni], acc[mi][ni], 0, 0, 0);

        asm volatile("s_waitcnt vmcnt(0)" ::: "memory");
        __syncthreads();
    }

    const int mtx = tn >> 10;
    const float* bp = mtx == 0 ? b0 : (mtx == 1 ? b1 : b2);
    const int crow0 = (lane >> 4) * 4;
    const int ccol = lane & 15;
#pragma unroll
    for (int mi = 0; mi < 4; ++mi) {
#pragma unroll
        for (int ni = 0; ni < 4; ++ni) {
            int n = tn + wn + ni * 16 + ccol;
            float bv = bp[n & 1023];
#pragma unroll
            for (int r = 0; r < 4; ++r) {
                int m = tm + wm + mi * 16 + crow0 + r;
                float val = acc[mi][ni][r] + bv;
                if (MODE == 0) {
                    ((float*)Cout)[(size_t)m * N + n] = val;
                } else {
                    if (mtx == 0) val *= QSCALE;   // q panel: fold softmax scale
                    int b = m >> 11, t = m & (T_LEN - 1);
                    int nn = n & 1023;
                    int h = nn >> 6, d = nn & 63;
                    ((u16*)Cout)[(size_t)mtx * 8388608 +
                                 ((size_t)(b * H_NUM + h) * T_LEN + t) * DK + d] = f2bf(val);
                }
            }
        }
    }
}

// ---------------- Flash attention, causal ----------------
// grid 512 (XCD-decoded), block 512 (8 waves). Block handles q-block pair
// {bx, 15-bx} of 128 rows; wave w owns 16 rows. KV tile = 64 keys,
// double-buffered; waves 4-7 stage K (global_load_lds, pre-swizzled source),
// waves 0-3 stage V (reg + 4x4 transpose + swizzled ds_write_b64).
// One barrier per tile. Softmax in exp2 domain (Q pre-scaled), defer-max,
// deferred row-sum reduction (once per seg, not per tile).
__global__ __launch_bounds__(512) void attn_fwd(const u16* __restrict__ q,
                                                const u16* __restrict__ k,
                                                const u16* __restrict__ v,
                                                u16* __restrict__ o) {
    __shared__ u16 lK[2][64 * 64];   // [key][d], 16B-window ^= key&7
    __shared__ u16 lV[2][64 * 64];   // [d][key], 16B-window ^= (d>>1)&7
    __shared__ u16 lP[8][16 * 64];   // per-wave P roundtrip (swizzled)

    const int tid = threadIdx.x, w = tid >> 6, lane = tid & 63;
    const int bid = blockIdx.x;
    const int idx = bid >> 3;                    // 0..63
    const int bh = (bid & 7) * 8 + (idx & 7);    // 8 bh per XCD (KV L2-resident)
    const int bx = idx >> 3;                     // 0..7

    const u16* qb = q + (size_t)bh * T_LEN * DK;
    const u16* kb = k + (size_t)bh * T_LEN * DK;
    const u16* vb = v + (size_t)bh * T_LEN * DK;

    const int g = lane >> 4;
    const int ccol = lane & 15;
    const int kg = tid >> 4;     // V-stage key group (waves 0-3: 0..15)
    const int dc = tid & 15;     // V-stage d group
    const int wk = w - 4;        // K-stage wave index (waves 4-7)
    const int b_ = bh >> 4, h_ = bh & 15;

    for (int seg = 0; seg < 2; ++seg) {
        const int qblk = seg ? (15 - bx) : bx;
        const int q0 = qblk * 128;
        const int ntiles = 2 * qblk + 2;         // always even
        const int rowbase = q0 + w * 16;

        bf16x8 qa[2];
#pragma unroll
        for (int kk = 0; kk < 2; ++kk)
            qa[kk] = *(const bf16x8*)(qb + (size_t)(rowbase + ccol) * DK + kk * 32 + g * 8);

        f32x4 oacc[4] = {};
        float mrow[4], lpart[4];
#pragma unroll
        for (int r = 0; r < 4; ++r) { mrow[r] = -1e30f; lpart[r] = 0.f; }

        // ---- prologue: issue tile 0 into buffer 0 ----
        u16x4 vr[4];
        if (w >= 4) {
#pragma unroll
            for (int r2 = 0; r2 < 2; ++r2) {
                int c = r2 * 256 + wk * 64 + lane;
                int row = c >> 3, ch = c & 7;
                __builtin_amdgcn_global_load_lds(
                    (AS1 const void*)(kb + (size_t)row * DK + (ch ^ (row & 7)) * 8),
                    (AS3 void*)(&lK[0][(r2 * 256 + wk * 64) * 8]), 16, 0, 0);
            }
        } else {
#pragma unroll
            for (int i = 0; i < 4; ++i)
                vr[i] = *(const u16x4*)(vb + (size_t)(kg * 4 + i) * DK + dc * 4);
        }

        for (int kt = 0; kt < ntiles; ++kt) {
            const int bf = kt & 1;
            const int kv0 = kt << 6;
            asm volatile("s_waitcnt vmcnt(0)" ::: "memory");
            if (w < 4) {   // scatter V(kt) -> lV[bf] (transposed, swizzled)
#pragma unroll
                for (int j = 0; j < 4; ++j) {
                    int d = dc * 4 + j;
                    u16x4 t4;
                    t4[0] = vr[0][j]; t4[1] = vr[1][j]; t4[2] = vr[2][j]; t4[3] = vr[3][j];
                    *(u16x4*)(&lV[bf][d * 64 +
                        (((kg >> 1) ^ ((d >> 1) & 7)) * 8 + (kg & 1) * 4)]) = t4;
                }
            }
            __syncthreads();

            // issue tile kt+1 (hidden under compute)
            if (kt + 1 < ntiles) {
                const int kvn = (kt + 1) << 6;
                if (w >= 4) {
#pragma unroll
                    for (int r2 = 0; r2 < 2; ++r2) {
                        int c = r2 * 256 + wk * 64 + lane;
                        int row = c >> 3, ch = c & 7;
                        __builtin_amdgcn_global_load_lds(
                            (AS1 const void*)(kb + (size_t)(kvn + row) * DK + (ch ^ (row & 7)) * 8),
                            (AS3 void*)(&lK[bf ^ 1][(r2 * 256 + wk * 64) * 8]), 16, 0, 0);
                    }
                } else {
#pragma unroll
                    for (int i = 0; i < 4; ++i)
                        vr[i] = *(const u16x4*)(vb + (size_t)(kvn + kg * 4 + i) * DK + dc * 4);
                }
            }

            if (kv0 < rowbase + 16) {   // tile not fully masked for this wave
                // S = Q K^T (exp2-domain scale already folded into Q)
                f32x4 sacc[4] = {};
#pragma unroll
                for (int nt = 0; nt < 4; ++nt)
#pragma unroll
                    for (int kk = 0; kk < 2; ++kk) {
                        bf16x8 kf = *(const bf16x8*)(&lK[bf][(nt * 16 + ccol) * 64 +
                                                     (((kk * 4 + g) ^ (ccol & 7)) * 8)]);
                        sacc[nt] = __builtin_amdgcn_mfma_f32_16x16x32_bf16(
                            qa[kk], kf, sacc[nt], 0, 0, 0);
                    }

                const bool full = (kv0 + 63) <= rowbase;  // wave-uniform
                float p[4][4], scal[4];
                bool anyresc = false;
#pragma unroll
                for (int r = 0; r < 4; ++r) {
                    int grow = rowbase + g * 4 + r;
                    float s[4], mx = -1e30f;
#pragma unroll
                    for (int nt = 0; nt < 4; ++nt) {
                        float sv = sacc[nt][r];
                        if (!full && (kv0 + nt * 16 + ccol > grow)) sv = -1e30f;
                        s[nt] = sv;
                        mx = fmaxf(mx, sv);
                    }
#pragma unroll
                    for (int off = 8; off; off >>= 1) mx = fmaxf(mx, __shfl_xor(mx, off));
                    const bool skiprow = (mx <= mrow[r] + 8.f);   // defer-max
                    float mnew = skiprow ? mrow[r] : mx;
                    float rsl = 0.f;
#pragma unroll
                    for (int nt = 0; nt < 4; ++nt) {
                        p[nt][r] = __builtin_amdgcn_exp2f(s[nt] - mnew);
                        rsl += p[nt][r];
                    }
                    scal[r] = skiprow ? 1.f : __builtin_amdgcn_exp2f(mrow[r] - mnew);
                    anyresc |= !skiprow;
                    lpart[r] = lpart[r] * scal[r] + rsl;   // per-lane partial sum
                    mrow[r] = mnew;
                }
                if (__any(anyresc)) {
#pragma unroll
                    for (int nt2 = 0; nt2 < 4; ++nt2)
#pragma unroll
                        for (int r = 0; r < 4; ++r) oacc[nt2][r] *= scal[r];
                }

                // P -> per-wave LDS (swizzled), read back as A-frags
#pragma unroll
                for (int nt = 0; nt < 4; ++nt)
#pragma unroll
                    for (int r = 0; r < 4; ++r) {
                        int qrow = g * 4 + r;
                        int swzq = ((qrow ^ (qrow >> 3)) & 7) * 8;
                        lP[w][qrow * 64 + ((nt * 16 + ccol) ^ swzq)] = f2bf(p[nt][r]);
                    }
                asm volatile("s_waitcnt lgkmcnt(0)" ::: "memory");
                bf16x8 pa[2];
                {
                    int swzr = (ccol ^ (ccol >> 3)) & 7;
#pragma unroll
                    for (int kk2 = 0; kk2 < 2; ++kk2)
                        pa[kk2] = *(const bf16x8*)(&lP[w][ccol * 64 +
                                                   ((kk2 * 4 + g) ^ swzr) * 8]);
                }
                const int vsw = (ccol >> 1) & 7;
#pragma unroll
                for (int nt2 = 0; nt2 < 4; ++nt2) {
#pragma unroll
                    for (int kk2 = 0; kk2 < 2; ++kk2) {
                        bf16x8 vf = *(const bf16x8*)(&lV[bf][(nt2 * 16 + ccol) * 64 +
                                                     (((kk2 * 4 + g) ^ vsw) * 8)]);
                        oacc[nt2] = __builtin_amdgcn_mfma_f32_16x16x32_bf16(
                            pa[kk2], vf, oacc[nt2], 0, 0, 0);
                    }
                }
            }
        }
        __syncthreads();  // protect LDS before next seg's prologue

        // epilogue: reduce deferred row-sums, normalize, store
#pragma unroll
        for (int r = 0; r < 4; ++r) {
            float rs = lpart[r];
#pragma unroll
            for (int off = 8; off; off >>= 1) rs += __shfl_xor(rs, off);
            float inv = 1.0f / rs;
            int trow = rowbase + g * 4 + r;
#pragma unroll
            for (int nt2 = 0; nt2 < 4; ++nt2) {
                float val = oacc[nt2][r] * inv;
                o[(size_t)(b_ * T_LEN + trow) * D_DIM + h_ * DK + nt2 * 16 + ccol] = f2bf(val);
            }
        }
    }
}

// ---------------- launch ----------------
extern "C" void kernel_launch(void* const* d_in, const int* in_sizes, int n_in,
                              void* d_out, int out_size, void* d_ws, size_t ws_size,
                              hipStream_t stream) {
    const float* x  = (const float*)d_in[0];
    const float* Wq = (const float*)d_in[2];
    const float* Wk = (const float*)d_in[3];
    const float* Wv = (const float*)d_in[4];
    const float* Wo = (const float*)d_in[5];
    const float* bq = (const float*)d_in[6];
    const float* bk = (const float*)d_in[7];
    const float* bv = (const float*)d_in[8];
    const float* bo = (const float*)d_in[9];

    char* ws = (char*)d_ws;
    u16* xb   = (u16*)(ws);                    // 16 MB, reused as attn output
    u16* wqb  = (u16*)(ws + 16777216);         // wq|wk|wv|wo contiguous 2MB each
    u16* wob  = (u16*)(ws + 23068672);
    u16* qws  = (u16*)(ws + 25165824);         // q|k|v contiguous 16MB each
    u16* kws  = (u16*)(ws + 41943040);
    u16* vws  = (u16*)(ws + 58720256);
    u16* attnb = xb;

    cvt_bf16<<<4096, 256, 0, stream>>>(x, xb, 1048576);
    cvt4_bf16<<<dim3(512, 4), 256, 0, stream>>>(Wq, Wk, Wv, Wo, wqb, 131072);

    // fused QKV projection: N = 3072 (wq|wk|wv panels), q pre-scaled
    gemm_bt<1><<<1536, 256, 0, stream>>>(xb, wqb, bq, bk, bv, qws, 8192, 3072, 1024, 64, 24);

    attn_fwd<<<512, 512, 0, stream>>>(qws, kws, vws, attnb);

    gemm_bt<0><<<512, 256, 0, stream>>>(attnb, wob, bo, bo, bo, d_out, 8192, 1024, 1024, 64, 8);
}

// Round 7
// 291.760 us; speedup vs baseline: 1.6711x; 1.1327x over previous
//
#include <hip/hip_runtime.h>
#include <hip/hip_bf16.h>

#define T_LEN 2048
#define D_DIM 1024
#define H_NUM 16
#define DK 64

typedef unsigned short u16;
typedef __bf16 bf16x8 __attribute__((ext_vector_type(8)));
typedef float f32x4 __attribute__((ext_vector_type(4)));
typedef u16 u16x8 __attribute__((ext_vector_type(8)));
typedef u16 u16x4 __attribute__((ext_vector_type(4)));

#define AS1 __attribute__((address_space(1)))
#define AS3 __attribute__((address_space(3)))

// Q pre-scale: 1/sqrt(64) * log2(e)  (softmax done in exp2 domain)
#define QSCALE 0.18033688011112042f

__device__ __forceinline__ u16 f2bf(float f) {
    unsigned u = __builtin_bit_cast(unsigned, f);
    unsigned rounding = 0x7FFFu + ((u >> 16) & 1u);
    return (u16)((u + rounding) >> 16);
}

// ---------------- f32 -> bf16 conversion (8 elems / thread) ----------------
__global__ __launch_bounds__(256) void cvt_bf16(const float* __restrict__ in,
                                                u16* __restrict__ out, int n8) {
    int i = blockIdx.x * blockDim.x + threadIdx.x;
    if (i >= n8) return;
    const float4* p = (const float4*)in + (size_t)i * 2;
    float4 a = p[0], b = p[1];
    u16x8 r;
    r[0] = f2bf(a.x); r[1] = f2bf(a.y); r[2] = f2bf(a.z); r[3] = f2bf(a.w);
    r[4] = f2bf(b.x); r[5] = f2bf(b.y); r[6] = f2bf(b.z); r[7] = f2bf(b.w);
    *((u16x8*)out + i) = r;
}

__global__ __launch_bounds__(256) void cvt4_bf16(const float* __restrict__ a,
                                                 const float* __restrict__ b,
                                                 const float* __restrict__ c,
                                                 const float* __restrict__ d,
                                                 u16* __restrict__ out, int n8per) {
    int s = blockIdx.y;
    const float* src = s == 0 ? a : (s == 1 ? b : (s == 2 ? c : d));
    int i = blockIdx.x * blockDim.x + threadIdx.x;
    if (i >= n8per) return;
    const float4* p = (const float4*)src + (size_t)i * 2;
    float4 x = p[0], y = p[1];
    u16x8 r;
    r[0] = f2bf(x.x); r[1] = f2bf(x.y); r[2] = f2bf(x.z); r[3] = f2bf(x.w);
    r[4] = f2bf(y.x); r[5] = f2bf(y.y); r[6] = f2bf(y.z); r[7] = f2bf(y.w);
    *((u16x8*)(out + (size_t)s * n8per * 8) + i) = r;
}

// ---------------- GEMM: C[M,N] = A[M,K] * W[N,K]^T + bias ----------------
// 2-phase double-buffered K-loop, XCD-aware 1-D grid decode.
template <int MODE>
__global__ __launch_bounds__(256) void gemm_bt(const u16* __restrict__ A,
                                               const u16* __restrict__ W,
                                               const float* __restrict__ b0,
                                               const float* __restrict__ b1,
                                               const float* __restrict__ b2,
                                               void* __restrict__ Cout,
                                               int M, int N, int K,
                                               int nxt, int nyt) {
    __shared__ u16 lA[2][128 * 32];
    __shared__ u16 lB[2][128 * 32];
    const int tid = threadIdx.x;
    const int w = tid >> 6, lane = tid & 63;

    const int bid = blockIdx.x;
    const int idx = bid >> 3;
    const int y = idx % nyt;
    const int x = (bid & 7) * (nxt >> 3) + idx / nyt;
    const int tm = x * 128;
    const int tn = y * 128;

    const int wm = (w >> 1) * 64, wn = (w & 1) * 64;
    const int kgrp = (lane >> 4) * 8;

    f32x4 acc[4][4] = {};

    auto stage = [&](int buf, int k0) {
#pragma unroll
        for (int r = 0; r < 2; ++r) {
            int c = r * 256 + tid;
            int row = c >> 2, col = (c & 3) * 8;
            __builtin_amdgcn_global_load_lds(
                (AS1 const void*)(A + (size_t)(tm + row) * K + k0 + col),
                (AS3 void*)(&lA[buf][(r * 256 + w * 64) * 8]), 16, 0, 0);
            __builtin_amdgcn_global_load_lds(
                (AS1 const void*)(W + (size_t)(tn + row) * K + k0 + col),
                (AS3 void*)(&lB[buf][(r * 256 + w * 64) * 8]), 16, 0, 0);
        }
    };

    stage(0, 0);
    asm volatile("s_waitcnt vmcnt(0)" ::: "memory");
    __syncthreads();

    const int niter = K >> 5;
    for (int it = 0; it < niter; ++it) {
        const int cur = it & 1;
        if (it + 1 < niter) stage(cur ^ 1, (it + 1) << 5);

        bf16x8 af[4], bfr[4];
#pragma unroll
        for (int i = 0; i < 4; ++i) {
            af[i]  = *(const bf16x8*)(&lA[cur][(wm + i * 16 + (lane & 15)) * 32 + kgrp]);
            bfr[i] = *(const bf16x8*)(&lB[cur][(wn + i * 16 + (lane & 15)) * 32 + kgrp]);
        }
#pragma unroll
        for (int mi = 0; mi < 4; ++mi)
#pragma unroll
            for (int ni = 0; ni < 4; ++ni)
                acc[mi][ni] = __builtin_amdgcn_mfma_f32_16x16x32_bf16(
                    af[mi], bfr[ni], acc[mi][ni], 0, 0, 0);

        asm volatile("s_waitcnt vmcnt(0)" ::: "memory");
        __syncthreads();
    }

    const int mtx = tn >> 10;
    const float* bp = mtx == 0 ? b0 : (mtx == 1 ? b1 : b2);
    const int crow0 = (lane >> 4) * 4;
    const int ccol = lane & 15;
#pragma unroll
    for (int mi = 0; mi < 4; ++mi) {
#pragma unroll
        for (int ni = 0; ni < 4; ++ni) {
            int n = tn + wn + ni * 16 + ccol;
            float bv = bp[n & 1023];
#pragma unroll
            for (int r = 0; r < 4; ++r) {
                int m = tm + wm + mi * 16 + crow0 + r;
                float val = acc[mi][ni][r] + bv;
                if (MODE == 0) {
                    ((float*)Cout)[(size_t)m * N + n] = val;
                } else {
                    if (mtx == 0) val *= QSCALE;   // q panel: fold softmax scale
                    int b = m >> 11, t = m & (T_LEN - 1);
                    int nn = n & 1023;
                    int h = nn >> 6, d = nn & 63;
                    ((u16*)Cout)[(size_t)mtx * 8388608 +
                                 ((size_t)(b * H_NUM + h) * T_LEN + t) * DK + d] = f2bf(val);
                }
            }
        }
    }
}

// ---------------- Flash attention, causal ----------------
// grid 512 (XCD-decoded), block 512 (8 waves). Block handles q-block pair
// {bx, 15-bx} of 128 rows; wave w owns 16 rows. KV tile 64, double-buffered.
// SWAPPED QK^T: S^T = mfma(K, Q) -> each lane holds 16 S-values for ONE q
// (q = ccol, k = nt*16 + g*4 + r). Softmax: 15 in-lane ops + 2 shuffles.
// P roundtrip: 4x ds_write_b64 (144B-stride rows), 2x ds_read_b128.
__global__ __launch_bounds__(512) void attn_fwd(const u16* __restrict__ q,
                                                const u16* __restrict__ k,
                                                const u16* __restrict__ v,
                                                u16* __restrict__ o) {
    __shared__ u16 lK[2][64 * 64];     // [key][d], 16B-window ^= key&7
    __shared__ u16 lV[2][64 * 64];     // [d][key], 16B-window ^= (d>>1)&7
    __shared__ u16 lP[8][16 * 72];     // per-wave P, row stride 144B (pad 16B)
    __shared__ float lSc[8][16];       // per-wave softmax-layout -> C-layout relay

    const int tid = threadIdx.x, w = tid >> 6, lane = tid & 63;
    const int bid = blockIdx.x;
    const int idx = bid >> 3;                    // 0..63
    const int bh = (bid & 7) * 8 + (idx & 7);    // 8 bh per XCD (KV L2-resident)
    const int bx = idx >> 3;                     // 0..7

    const u16* qb = q + (size_t)bh * T_LEN * DK;
    const u16* kb = k + (size_t)bh * T_LEN * DK;
    const u16* vb = v + (size_t)bh * T_LEN * DK;

    const int g = lane >> 4;
    const int ccol = lane & 15;
    const int kg = tid >> 4;     // V-stage key group (waves 0-3: 0..15)
    const int dc = tid & 15;     // V-stage d group
    const int wk = w - 4;        // K-stage wave index (waves 4-7)
    const int b_ = bh >> 4, h_ = bh & 15;

    for (int seg = 0; seg < 2; ++seg) {
        const int qblk = seg ? (15 - bx) : bx;
        const int q0 = qblk * 128;
        const int ntiles = 2 * qblk + 2;         // always even
        const int rowbase = q0 + w * 16;
        const int myq = rowbase + ccol;          // this lane's q row (softmax)

        bf16x8 qa[2];
#pragma unroll
        for (int kk = 0; kk < 2; ++kk)
            qa[kk] = *(const bf16x8*)(qb + (size_t)(rowbase + ccol) * DK + kk * 32 + g * 8);

        f32x4 oacc[4] = {};
        float mrow = -1e30f, lpart = 0.f;        // scalar state: q = ccol

        // ---- prologue: issue tile 0 into buffer 0 ----
        u16x4 vr[4];
        if (w >= 4) {
#pragma unroll
            for (int r2 = 0; r2 < 2; ++r2) {
                int c = r2 * 256 + wk * 64 + lane;
                int row = c >> 3, ch = c & 7;
                __builtin_amdgcn_global_load_lds(
                    (AS1 const void*)(kb + (size_t)row * DK + (ch ^ (row & 7)) * 8),
                    (AS3 void*)(&lK[0][(r2 * 256 + wk * 64) * 8]), 16, 0, 0);
            }
        } else {
#pragma unroll
            for (int i = 0; i < 4; ++i)
                vr[i] = *(const u16x4*)(vb + (size_t)(kg * 4 + i) * DK + dc * 4);
        }

        for (int kt = 0; kt < ntiles; ++kt) {
            const int bf = kt & 1;
            const int kv0 = kt << 6;
            asm volatile("s_waitcnt vmcnt(0)" ::: "memory");
            if (w < 4) {   // scatter V(kt) -> lV[bf] (transposed, swizzled)
#pragma unroll
                for (int j = 0; j < 4; ++j) {
                    int d = dc * 4 + j;
                    u16x4 t4;
                    t4[0] = vr[0][j]; t4[1] = vr[1][j]; t4[2] = vr[2][j]; t4[3] = vr[3][j];
                    *(u16x4*)(&lV[bf][d * 64 +
                        (((kg >> 1) ^ ((d >> 1) & 7)) * 8 + (kg & 1) * 4)]) = t4;
                }
            }
            __syncthreads();

            // issue tile kt+1 (hidden under compute)
            if (kt + 1 < ntiles) {
                const int kvn = (kt + 1) << 6;
                if (w >= 4) {
#pragma unroll
                    for (int r2 = 0; r2 < 2; ++r2) {
                        int c = r2 * 256 + wk * 64 + lane;
                        int row = c >> 3, ch = c & 7;
                        __builtin_amdgcn_global_load_lds(
                            (AS1 const void*)(kb + (size_t)(kvn + row) * DK + (ch ^ (row & 7)) * 8),
                            (AS3 void*)(&lK[bf ^ 1][(r2 * 256 + wk * 64) * 8]), 16, 0, 0);
                    }
                } else {
#pragma unroll
                    for (int i = 0; i < 4; ++i)
                        vr[i] = *(const u16x4*)(vb + (size_t)(kvn + kg * 4 + i) * DK + dc * 4);
                }
            }

            if (kv0 < rowbase + 16) {   // tile not fully masked for this wave
                // S^T = K Q^T : C col = q-local (ccol), row = k-local (g*4+r)
                f32x4 sacc[4] = {};
                __builtin_amdgcn_s_setprio(1);
#pragma unroll
                for (int nt = 0; nt < 4; ++nt)
#pragma unroll
                    for (int kk = 0; kk < 2; ++kk) {
                        bf16x8 kf = *(const bf16x8*)(&lK[bf][(nt * 16 + ccol) * 64 +
                                                     (((kk * 4 + g) ^ (ccol & 7)) * 8)]);
                        sacc[nt] = __builtin_amdgcn_mfma_f32_16x16x32_bf16(
                            kf, qa[kk], sacc[nt], 0, 0, 0);
                    }
                __builtin_amdgcn_s_setprio(0);

                const bool full = (kv0 + 63) <= rowbase;  // wave-uniform
                // mask + in-lane max over this lane's 16 k-values
                float mx = -1e30f;
#pragma unroll
                for (int nt = 0; nt < 4; ++nt)
#pragma unroll
                    for (int r = 0; r < 4; ++r) {
                        float sv = sacc[nt][r];
                        if (!full && (kv0 + nt * 16 + g * 4 + r > myq)) sv = -1e30f;
                        sacc[nt][r] = sv;
                        mx = fmaxf(mx, sv);
                    }
                mx = fmaxf(mx, __shfl_xor(mx, 16));
                mx = fmaxf(mx, __shfl_xor(mx, 32));

                const bool skiprow = (mx <= mrow + 8.f);   // defer-max (T13)
                float mnew = skiprow ? mrow : mx;
                float p[4][4];
                float rsl = 0.f;
#pragma unroll
                for (int nt = 0; nt < 4; ++nt)
#pragma unroll
                    for (int r = 0; r < 4; ++r) {
                        float pv = __builtin_amdgcn_exp2f(sacc[nt][r] - mnew);
                        p[nt][r] = pv;
                        rsl += pv;
                    }
                float scal = skiprow ? 1.f : __builtin_amdgcn_exp2f(mrow - mnew);
                lpart = lpart * scal + rsl;
                mrow = mnew;

                // relay scal (q=ccol layout) -> C-layout; write P rows
                if (lane < 16) lSc[w][lane] = scal;
#pragma unroll
                for (int nt = 0; nt < 4; ++nt) {
                    u16x4 t4;
                    t4[0] = f2bf(p[nt][0]); t4[1] = f2bf(p[nt][1]);
                    t4[2] = f2bf(p[nt][2]); t4[3] = f2bf(p[nt][3]);
                    *(u16x4*)(&lP[w][ccol * 72 + nt * 16 + g * 4]) = t4;
                }
                asm volatile("s_waitcnt lgkmcnt(0)" ::: "memory");

                f32x4 scalC = *(const f32x4*)(&lSc[w][g * 4]);
                if (__any(!skiprow)) {
#pragma unroll
                    for (int nt2 = 0; nt2 < 4; ++nt2)
#pragma unroll
                        for (int r = 0; r < 4; ++r) oacc[nt2][r] *= scalC[r];
                }

                bf16x8 pa[2];
#pragma unroll
                for (int kk2 = 0; kk2 < 2; ++kk2)
                    pa[kk2] = *(const bf16x8*)(&lP[w][ccol * 72 + kk2 * 32 + g * 8]);

                const int vsw = (ccol >> 1) & 7;
                __builtin_amdgcn_s_setprio(1);
#pragma unroll
                for (int nt2 = 0; nt2 < 4; ++nt2) {
#pragma unroll
                    for (int kk2 = 0; kk2 < 2; ++kk2) {
                        bf16x8 vf = *(const bf16x8*)(&lV[bf][(nt2 * 16 + ccol) * 64 +
                                                     (((kk2 * 4 + g) ^ vsw) * 8)]);
                        oacc[nt2] = __builtin_amdgcn_mfma_f32_16x16x32_bf16(
                            pa[kk2], vf, oacc[nt2], 0, 0, 0);
                    }
                }
                __builtin_amdgcn_s_setprio(0);
            }
        }
        __syncthreads();  // protect LDS before next seg's prologue

        // epilogue: reduce deferred row-sum (2 shuffles), relay to C-layout
        float rs = lpart;
        rs += __shfl_xor(rs, 16);
        rs += __shfl_xor(rs, 32);
        if (lane < 16) lSc[w][lane] = rs;
        asm volatile("s_waitcnt lgkmcnt(0)" ::: "memory");
        f32x4 rsC = *(const f32x4*)(&lSc[w][g * 4]);
#pragma unroll
        for (int r = 0; r < 4; ++r) {
            float inv = 1.0f / rsC[r];
            int trow = rowbase + g * 4 + r;
#pragma unroll
            for (int nt2 = 0; nt2 < 4; ++nt2) {
                float val = oacc[nt2][r] * inv;
                o[(size_t)(b_ * T_LEN + trow) * D_DIM + h_ * DK + nt2 * 16 + ccol] = f2bf(val);
            }
        }
        __syncthreads();  // lSc reuse guard across segs (same wave only, cheap)
    }
}

// ---------------- launch ----------------
extern "C" void kernel_launch(void* const* d_in, const int* in_sizes, int n_in,
                              void* d_out, int out_size, void* d_ws, size_t ws_size,
                              hipStream_t stream) {
    const float* x  = (const float*)d_in[0];
    const float* Wq = (const float*)d_in[2];
    const float* Wk = (const float*)d_in[3];
    const float* Wv = (const float*)d_in[4];
    const float* Wo = (const float*)d_in[5];
    const float* bq = (const float*)d_in[6];
    const float* bk = (const float*)d_in[7];
    const float* bv = (const float*)d_in[8];
    const float* bo = (const float*)d_in[9];

    char* ws = (char*)d_ws;
    u16* xb   = (u16*)(ws);                    // 16 MB, reused as attn output
    u16* wqb  = (u16*)(ws + 16777216);         // wq|wk|wv|wo contiguous 2MB each
    u16* wob  = (u16*)(ws + 23068672);
    u16* qws  = (u16*)(ws + 25165824);         // q|k|v contiguous 16MB each
    u16* kws  = (u16*)(ws + 41943040);
    u16* vws  = (u16*)(ws + 58720256);
    u16* attnb = xb;

    cvt_bf16<<<4096, 256, 0, stream>>>(x, xb, 1048576);
    cvt4_bf16<<<dim3(512, 4), 256, 0, stream>>>(Wq, Wk, Wv, Wo, wqb, 131072);

    // fused QKV projection: N = 3072 (wq|wk|wv panels), q pre-scaled
    gemm_bt<1><<<1536, 256, 0, stream>>>(xb, wqb, bq, bk, bv, qws, 8192, 3072, 1024, 64, 24);

    attn_fwd<<<512, 512, 0, stream>>>(qws, kws, vws, attnb);

    gemm_bt<0><<<512, 256, 0, stream>>>(attnb, wob, bo, bo, bo, d_out, 8192, 1024, 1024, 64, 8);
}

// Round 8
// 273.496 us; speedup vs baseline: 1.7826x; 1.0668x over previous
//
#include <hip/hip_runtime.h>
#include <hip/hip_bf16.h>

#define T_LEN 2048
#define D_DIM 1024
#define H_NUM 16
#define DK 64

typedef unsigned short u16;
typedef __bf16 bf16x8 __attribute__((ext_vector_type(8)));
typedef float f32x4 __attribute__((ext_vector_type(4)));
typedef u16 u16x8 __attribute__((ext_vector_type(8)));
typedef u16 u16x4 __attribute__((ext_vector_type(4)));

#define AS1 __attribute__((address_space(1)))
#define AS3 __attribute__((address_space(3)))

// Q pre-scale: 1/sqrt(64) * log2(e)  (softmax done in exp2 domain)
#define QSCALE 0.18033688011112042f

__device__ __forceinline__ u16 f2bf(float f) {
    unsigned u = __builtin_bit_cast(unsigned, f);
    unsigned rounding = 0x7FFFu + ((u >> 16) & 1u);
    return (u16)((u + rounding) >> 16);
}

// ---------------- f32 -> bf16 conversion (8 elems / thread) ----------------
__global__ __launch_bounds__(256) void cvt_bf16(const float* __restrict__ in,
                                                u16* __restrict__ out, int n8) {
    int i = blockIdx.x * blockDim.x + threadIdx.x;
    if (i >= n8) return;
    const float4* p = (const float4*)in + (size_t)i * 2;
    float4 a = p[0], b = p[1];
    u16x8 r;
    r[0] = f2bf(a.x); r[1] = f2bf(a.y); r[2] = f2bf(a.z); r[3] = f2bf(a.w);
    r[4] = f2bf(b.x); r[5] = f2bf(b.y); r[6] = f2bf(b.z); r[7] = f2bf(b.w);
    *((u16x8*)out + i) = r;
}

__global__ __launch_bounds__(256) void cvt4_bf16(const float* __restrict__ a,
                                                 const float* __restrict__ b,
                                                 const float* __restrict__ c,
                                                 const float* __restrict__ d,
                                                 u16* __restrict__ out, int n8per) {
    int s = blockIdx.y;
    const float* src = s == 0 ? a : (s == 1 ? b : (s == 2 ? c : d));
    int i = blockIdx.x * blockDim.x + threadIdx.x;
    if (i >= n8per) return;
    const float4* p = (const float4*)src + (size_t)i * 2;
    float4 x = p[0], y = p[1];
    u16x8 r;
    r[0] = f2bf(x.x); r[1] = f2bf(x.y); r[2] = f2bf(x.z); r[3] = f2bf(x.w);
    r[4] = f2bf(y.x); r[5] = f2bf(y.y); r[6] = f2bf(y.z); r[7] = f2bf(y.w);
    *((u16x8*)(out + (size_t)s * n8per * 8) + i) = r;
}

// ============ QKV GEMM: 256x256 tile, BK=64, 8 waves, 8-phase pipeline ======
// C[M=8192, N=3072] = A[M,K=1024] * W[N,K]^T + bias, bf16 out permuted to
// [mtx][B,H,T,DK], q panel pre-scaled by QSCALE.
// K-tile = 64 split into 2 K-halves of 32 (A-h, B-h = 256x32 = 16 KB each).
// LDS: 2 parities x {A-h0, A-h1, B-h0, B-h1} = 128 KB. Per phase: ds_read
// frags + stage 1 half + raw barrier + MFMA(16) + barrier. vmcnt(4) once per
// K-tile (invariant: every half forced >=3 phases before first read).
// Swizzle (both sides): k-group ^= (row>>1)&3 within each 16KB half.
__global__ __launch_bounds__(512) void gemm_qkv(const u16* __restrict__ A,
                                                const u16* __restrict__ W,
                                                const float* __restrict__ b0,
                                                const float* __restrict__ b1,
                                                const float* __restrict__ b2,
                                                u16* __restrict__ Cout) {
    __shared__ u16 L[2][4][8192];   // [parity][A0,A1,B0,B1][256 rows x 32 k]
    const int tid = threadIdx.x, w = tid >> 6, lane = tid & 63;
    const int sw = (blockIdx.x & 7) * 48 + (blockIdx.x >> 3);  // XCD-chunked
    const int xm = sw / 12, yn = sw % 12;
    const int tm = xm * 256, tn = yn * 256;
    const int wr = w >> 2, wc = w & 3;          // wave grid 2M x 4N
    const int g = lane >> 4, ccol = lane & 15;
    const int gsw = (g ^ ((ccol >> 1) & 3)) * 8;   // read-side swizzle
    const int K = 1024, NT = 16;

    const u16* Ab = A + (size_t)tm * K;
    const u16* Wb = W + (size_t)tn * K;

    // staging constants: thread covers dest bytes [tid*16] and [8192+tid*16]
    const int srow = w * 16 + (lane >> 2);
    const int skk  = (((lane & 3) ^ ((lane >> 3) & 3))) * 8;  // inverse swizzle

    f32x4 acc[8][4] = {};

    auto stage = [&](const u16* gb, int k0, int ksub, u16* reg) {
#pragma unroll
        for (int h2 = 0; h2 < 2; ++h2) {
            __builtin_amdgcn_global_load_lds(
                (AS1 const void*)(gb + (size_t)(h2 * 128 + srow) * K + k0 + ksub * 32 + skk),
                (AS3 void*)(reg + h2 * 4096 + w * 512), 16, 0, 0);
        }
    };

    // prologue: tile0 all 4 halves + tile1 h0 pair (order matters for vmcnt)
    stage(Ab, 0, 0, L[0][0]);
    stage(Wb, 0, 0, L[0][2]);
    stage(Ab, 0, 1, L[0][1]);
    stage(Wb, 0, 1, L[0][3]);
    stage(Ab, 64, 0, L[1][0]);
    stage(Wb, 64, 0, L[1][2]);
    asm volatile("s_waitcnt vmcnt(4)" ::: "memory");   // tile0 forced complete
    __builtin_amdgcn_s_barrier();

    bf16x8 bfr[4];
    for (int t = 0; t < NT; ++t) {
        const int par = t & 1;
        u16* LA0 = L[par][0]; u16* LA1 = L[par][1];
        u16* LB0 = L[par][2]; u16* LB1 = L[par][3];
#pragma unroll
        for (int p = 0; p < 4; ++p) {
            const int mh = (p & 1) * 4;
            u16* LAk = (p >> 1) ? LA1 : LA0;
            u16* LBk = (p >> 1) ? LB1 : LB0;
            bf16x8 af[4];
#pragma unroll
            for (int i = 0; i < 4; ++i)
                af[i] = *(const bf16x8*)(LAk + (wr * 128 + (mh + i) * 16 + ccol) * 32 + gsw);
            if ((p & 1) == 0) {
#pragma unroll
                for (int i = 0; i < 4; ++i)
                    bfr[i] = *(const bf16x8*)(LBk + (wc * 64 + i * 16 + ccol) * 32 + gsw);
            }
            // stage one half-tile (early-restage into dead regions)
            if (p == 0)      { if (t + 1 < NT) stage(Ab, (t + 1) * 64, 1, L[(t + 1) & 1][1]); }
            else if (p == 1) { if (t + 1 < NT) stage(Wb, (t + 1) * 64, 1, L[(t + 1) & 1][3]); }
            else if (p == 2) { if (t + 2 < NT) stage(Ab, (t + 2) * 64, 0, L[par][0]); }
            else {
                if (t + 2 < NT) stage(Wb, (t + 2) * 64, 0, L[par][2]);
                if (t < NT - 2) asm volatile("s_waitcnt vmcnt(4)" ::: "memory");
                else            asm volatile("s_waitcnt vmcnt(0)" ::: "memory");
            }
            __builtin_amdgcn_s_barrier();
            asm volatile("s_waitcnt lgkmcnt(0)" ::: "memory");
            __builtin_amdgcn_sched_barrier(0);
            __builtin_amdgcn_s_setprio(1);
#pragma unroll
            for (int ni = 0; ni < 4; ++ni)
#pragma unroll
                for (int mi = 0; mi < 4; ++mi)
                    acc[mh + mi][ni] = __builtin_amdgcn_mfma_f32_16x16x32_bf16(
                        af[mi], bfr[ni], acc[mh + mi][ni], 0, 0, 0);
            __builtin_amdgcn_s_setprio(0);
            __builtin_amdgcn_s_barrier();
        }
    }

    // epilogue: bias + permute to [mtx][B,H,T,DK] bf16 (q panel pre-scaled)
    const int mtx = yn >> 2;
    const float* bp = mtx == 0 ? b0 : (mtx == 1 ? b1 : b2);
#pragma unroll
    for (int mi = 0; mi < 8; ++mi) {
#pragma unroll
        for (int ni = 0; ni < 4; ++ni) {
            int nn = (tn + wc * 64 + ni * 16 + ccol) & 1023;
            float bv = bp[nn];
            int h = nn >> 6, d = nn & 63;
#pragma unroll
            for (int r = 0; r < 4; ++r) {
                int m = tm + wr * 128 + mi * 16 + g * 4 + r;
                float val = acc[mi][ni][r] + bv;
                if (mtx == 0) val *= QSCALE;
                int b = m >> 11, tt = m & (T_LEN - 1);
                Cout[(size_t)mtx * 8388608 +
                     ((size_t)(b * H_NUM + h) * T_LEN + tt) * DK + d] = f2bf(val);
            }
        }
    }
}

// ---------------- GEMM (final projection): 128x128, 2-phase ----------------
__global__ __launch_bounds__(256) void gemm_bt(const u16* __restrict__ A,
                                               const u16* __restrict__ W,
                                               const float* __restrict__ b0,
                                               float* __restrict__ Cout,
                                               int M, int N, int K,
                                               int nxt, int nyt) {
    __shared__ u16 lA[2][128 * 32];
    __shared__ u16 lB[2][128 * 32];
    const int tid = threadIdx.x;
    const int w = tid >> 6, lane = tid & 63;

    const int bid = blockIdx.x;
    const int idx = bid >> 3;
    const int y = idx % nyt;
    const int x = (bid & 7) * (nxt >> 3) + idx / nyt;
    const int tm = x * 128;
    const int tn = y * 128;

    const int wm = (w >> 1) * 64, wn = (w & 1) * 64;
    const int kgrp = (lane >> 4) * 8;

    f32x4 acc[4][4] = {};

    auto stage = [&](int buf, int k0) {
#pragma unroll
        for (int r = 0; r < 2; ++r) {
            int c = r * 256 + tid;
            int row = c >> 2, col = (c & 3) * 8;
            __builtin_amdgcn_global_load_lds(
                (AS1 const void*)(A + (size_t)(tm + row) * K + k0 + col),
                (AS3 void*)(&lA[buf][(r * 256 + w * 64) * 8]), 16, 0, 0);
            __builtin_amdgcn_global_load_lds(
                (AS1 const void*)(W + (size_t)(tn + row) * K + k0 + col),
                (AS3 void*)(&lB[buf][(r * 256 + w * 64) * 8]), 16, 0, 0);
        }
    };

    stage(0, 0);
    asm volatile("s_waitcnt vmcnt(0)" ::: "memory");
    __syncthreads();

    const int niter = K >> 5;
    for (int it = 0; it < niter; ++it) {
        const int cur = it & 1;
        if (it + 1 < niter) stage(cur ^ 1, (it + 1) << 5);

        bf16x8 af[4], bfr[4];
#pragma unroll
        for (int i = 0; i < 4; ++i) {
            af[i]  = *(const bf16x8*)(&lA[cur][(wm + i * 16 + (lane & 15)) * 32 + kgrp]);
            bfr[i] = *(const bf16x8*)(&lB[cur][(wn + i * 16 + (lane & 15)) * 32 + kgrp]);
        }
#pragma unroll
        for (int mi = 0; mi < 4; ++mi)
#pragma unroll
            for (int ni = 0; ni < 4; ++ni)
                acc[mi][ni] = __builtin_amdgcn_mfma_f32_16x16x32_bf16(
                    af[mi], bfr[ni], acc[mi][ni], 0, 0, 0);

        asm volatile("s_waitcnt vmcnt(0)" ::: "memory");
        __syncthreads();
    }

    const int crow0 = (lane >> 4) * 4;
    const int ccol = lane & 15;
#pragma unroll
    for (int mi = 0; mi < 4; ++mi) {
#pragma unroll
        for (int ni = 0; ni < 4; ++ni) {
            int n = tn + wn + ni * 16 + ccol;
            float bv = b0[n & 1023];
#pragma unroll
            for (int r = 0; r < 4; ++r) {
                int m = tm + wm + mi * 16 + crow0 + r;
                Cout[(size_t)m * N + n] = acc[mi][ni][r] + bv;
            }
        }
    }
}

// ---------------- Flash attention, causal ----------------
// grid 512 (XCD-decoded), block 512 (8 waves). Block handles q-block pair
// {bx, 15-bx} of 128 rows; wave w owns 16 rows. KV tile 64, double-buffered.
// SWAPPED QK^T: S^T = mfma(K, Q) -> each lane holds 16 S-values for ONE q.
__global__ __launch_bounds__(512) void attn_fwd(const u16* __restrict__ q,
                                                const u16* __restrict__ k,
                                                const u16* __restrict__ v,
                                                u16* __restrict__ o) {
    __shared__ u16 lK[2][64 * 64];     // [key][d], 16B-window ^= key&7
    __shared__ u16 lV[2][64 * 64];     // [d][key], 16B-window ^= (d>>1)&7
    __shared__ u16 lP[8][16 * 72];     // per-wave P, row stride 144B
    __shared__ float lSc[8][16];       // softmax-layout -> C-layout relay

    const int tid = threadIdx.x, w = tid >> 6, lane = tid & 63;
    const int bid = blockIdx.x;
    const int idx = bid >> 3;
    const int bh = (bid & 7) * 8 + (idx & 7);    // 8 bh per XCD
    const int bx = idx >> 3;

    const u16* qb = q + (size_t)bh * T_LEN * DK;
    const u16* kb = k + (size_t)bh * T_LEN * DK;
    const u16* vb = v + (size_t)bh * T_LEN * DK;

    const int g = lane >> 4;
    const int ccol = lane & 15;
    const int kg = tid >> 4;
    const int dc = tid & 15;
    const int wk = w - 4;
    const int b_ = bh >> 4, h_ = bh & 15;

    for (int seg = 0; seg < 2; ++seg) {
        const int qblk = seg ? (15 - bx) : bx;
        const int q0 = qblk * 128;
        const int ntiles = 2 * qblk + 2;
        const int rowbase = q0 + w * 16;
        const int myq = rowbase + ccol;

        bf16x8 qa[2];
#pragma unroll
        for (int kk = 0; kk < 2; ++kk)
            qa[kk] = *(const bf16x8*)(qb + (size_t)(rowbase + ccol) * DK + kk * 32 + g * 8);

        f32x4 oacc[4] = {};
        float mrow = -1e30f, lpart = 0.f;

        u16x4 vr[4];
        if (w >= 4) {
#pragma unroll
            for (int r2 = 0; r2 < 2; ++r2) {
                int c = r2 * 256 + wk * 64 + lane;
                int row = c >> 3, ch = c & 7;
                __builtin_amdgcn_global_load_lds(
                    (AS1 const void*)(kb + (size_t)row * DK + (ch ^ (row & 7)) * 8),
                    (AS3 void*)(&lK[0][(r2 * 256 + wk * 64) * 8]), 16, 0, 0);
            }
        } else {
#pragma unroll
            for (int i = 0; i < 4; ++i)
                vr[i] = *(const u16x4*)(vb + (size_t)(kg * 4 + i) * DK + dc * 4);
        }

        for (int kt = 0; kt < ntiles; ++kt) {
            const int bf = kt & 1;
            const int kv0 = kt << 6;
            asm volatile("s_waitcnt vmcnt(0)" ::: "memory");
            if (w < 4) {
#pragma unroll
                for (int j = 0; j < 4; ++j) {
                    int d = dc * 4 + j;
                    u16x4 t4;
                    t4[0] = vr[0][j]; t4[1] = vr[1][j]; t4[2] = vr[2][j]; t4[3] = vr[3][j];
                    *(u16x4*)(&lV[bf][d * 64 +
                        (((kg >> 1) ^ ((d >> 1) & 7)) * 8 + (kg & 1) * 4)]) = t4;
                }
            }
            __syncthreads();

            if (kt + 1 < ntiles) {
                const int kvn = (kt + 1) << 6;
                if (w >= 4) {
#pragma unroll
                    for (int r2 = 0; r2 < 2; ++r2) {
                        int c = r2 * 256 + wk * 64 + lane;
                        int row = c >> 3, ch = c & 7;
                        __builtin_amdgcn_global_load_lds(
                            (AS1 const void*)(kb + (size_t)(kvn + row) * DK + (ch ^ (row & 7)) * 8),
                            (AS3 void*)(&lK[bf ^ 1][(r2 * 256 + wk * 64) * 8]), 16, 0, 0);
                    }
                } else {
#pragma unroll
                    for (int i = 0; i < 4; ++i)
                        vr[i] = *(const u16x4*)(vb + (size_t)(kvn + kg * 4 + i) * DK + dc * 4);
                }
            }

            if (kv0 < rowbase + 16) {
                f32x4 sacc[4] = {};
                __builtin_amdgcn_s_setprio(1);
#pragma unroll
                for (int nt = 0; nt < 4; ++nt)
#pragma unroll
                    for (int kk = 0; kk < 2; ++kk) {
                        bf16x8 kf = *(const bf16x8*)(&lK[bf][(nt * 16 + ccol) * 64 +
                                                     (((kk * 4 + g) ^ (ccol & 7)) * 8)]);
                        sacc[nt] = __builtin_amdgcn_mfma_f32_16x16x32_bf16(
                            kf, qa[kk], sacc[nt], 0, 0, 0);
                    }
                __builtin_amdgcn_s_setprio(0);

                const bool full = (kv0 + 63) <= rowbase;
                float mx = -1e30f;
#pragma unroll
                for (int nt = 0; nt < 4; ++nt)
#pragma unroll
                    for (int r = 0; r < 4; ++r) {
                        float sv = sacc[nt][r];
                        if (!full && (kv0 + nt * 16 + g * 4 + r > myq)) sv = -1e30f;
                        sacc[nt][r] = sv;
                        mx = fmaxf(mx, sv);
                    }
                mx = fmaxf(mx, __shfl_xor(mx, 16));
                mx = fmaxf(mx, __shfl_xor(mx, 32));

                const bool skiprow = (mx <= mrow + 8.f);
                float mnew = skiprow ? mrow : mx;
                float p[4][4];
                float rsl = 0.f;
#pragma unroll
                for (int nt = 0; nt < 4; ++nt)
#pragma unroll
                    for (int r = 0; r < 4; ++r) {
                        float pv = __builtin_amdgcn_exp2f(sacc[nt][r] - mnew);
                        p[nt][r] = pv;
                        rsl += pv;
                    }
                float scal = skiprow ? 1.f : __builtin_amdgcn_exp2f(mrow - mnew);
                lpart = lpart * scal + rsl;
                mrow = mnew;

                if (lane < 16) lSc[w][lane] = scal;
#pragma unroll
                for (int nt = 0; nt < 4; ++nt) {
                    u16x4 t4;
                    t4[0] = f2bf(p[nt][0]); t4[1] = f2bf(p[nt][1]);
                    t4[2] = f2bf(p[nt][2]); t4[3] = f2bf(p[nt][3]);
                    *(u16x4*)(&lP[w][ccol * 72 + nt * 16 + g * 4]) = t4;
                }
                asm volatile("s_waitcnt lgkmcnt(0)" ::: "memory");

                f32x4 scalC = *(const f32x4*)(&lSc[w][g * 4]);
                if (__any(!skiprow)) {
#pragma unroll
                    for (int nt2 = 0; nt2 < 4; ++nt2)
#pragma unroll
                        for (int r = 0; r < 4; ++r) oacc[nt2][r] *= scalC[r];
                }

                bf16x8 pa[2];
#pragma unroll
                for (int kk2 = 0; kk2 < 2; ++kk2)
                    pa[kk2] = *(const bf16x8*)(&lP[w][ccol * 72 + kk2 * 32 + g * 8]);

                const int vsw = (ccol >> 1) & 7;
                __builtin_amdgcn_s_setprio(1);
#pragma unroll
                for (int nt2 = 0; nt2 < 4; ++nt2) {
#pragma unroll
                    for (int kk2 = 0; kk2 < 2; ++kk2) {
                        bf16x8 vf = *(const bf16x8*)(&lV[bf][(nt2 * 16 + ccol) * 64 +
                                                     (((kk2 * 4 + g) ^ vsw) * 8)]);
                        oacc[nt2] = __builtin_amdgcn_mfma_f32_16x16x32_bf16(
                            pa[kk2], vf, oacc[nt2], 0, 0, 0);
                    }
                }
                __builtin_amdgcn_s_setprio(0);
            }
        }
        __syncthreads();

        float rs = lpart;
        rs += __shfl_xor(rs, 16);
        rs += __shfl_xor(rs, 32);
        if (lane < 16) lSc[w][lane] = rs;
        asm volatile("s_waitcnt lgkmcnt(0)" ::: "memory");
        f32x4 rsC = *(const f32x4*)(&lSc[w][g * 4]);
#pragma unroll
        for (int r = 0; r < 4; ++r) {
            float inv = 1.0f / rsC[r];
            int trow = rowbase + g * 4 + r;
#pragma unroll
            for (int nt2 = 0; nt2 < 4; ++nt2) {
                float val = oacc[nt2][r] * inv;
                o[(size_t)(b_ * T_LEN + trow) * D_DIM + h_ * DK + nt2 * 16 + ccol] = f2bf(val);
            }
        }
        __syncthreads();
    }
}

// ---------------- launch ----------------
extern "C" void kernel_launch(void* const* d_in, const int* in_sizes, int n_in,
                              void* d_out, int out_size, void* d_ws, size_t ws_size,
                              hipStream_t stream) {
    const float* x  = (const float*)d_in[0];
    const float* Wq = (const float*)d_in[2];
    const float* Wk = (const float*)d_in[3];
    const float* Wv = (const float*)d_in[4];
    const float* Wo = (const float*)d_in[5];
    const float* bq = (const float*)d_in[6];
    const float* bk = (const float*)d_in[7];
    const float* bv = (const float*)d_in[8];
    const float* bo = (const float*)d_in[9];

    char* ws = (char*)d_ws;
    u16* xb   = (u16*)(ws);                    // 16 MB, reused as attn output
    u16* wqb  = (u16*)(ws + 16777216);         // wq|wk|wv|wo contiguous 2MB each
    u16* wob  = (u16*)(ws + 23068672);
    u16* qws  = (u16*)(ws + 25165824);         // q|k|v contiguous 16MB each
    u16* kws  = (u16*)(ws + 41943040);
    u16* vws  = (u16*)(ws + 58720256);
    u16* attnb = xb;

    cvt_bf16<<<4096, 256, 0, stream>>>(x, xb, 1048576);
    cvt4_bf16<<<dim3(512, 4), 256, 0, stream>>>(Wq, Wk, Wv, Wo, wqb, 131072);

    // fused QKV projection: 256^2 8-phase pipeline (N = 3072 panels)
    gemm_qkv<<<384, 512, 0, stream>>>(xb, wqb, bq, bk, bv, qws);

    attn_fwd<<<512, 512, 0, stream>>>(qws, kws, vws, attnb);

    gemm_bt<<<512, 256, 0, stream>>>(attnb, wob, bo, (float*)d_out, 8192, 1024, 1024, 64, 8);
}